// Round 3
// baseline (124.988 us; speedup 1.0000x reference)
//
#include <hip/hip_runtime.h>
#include <cstdint>
#include <cstddef>

// Problem dims
#define B_ROWS 65536
#define D_IN   784
#define KP     832      // D_IN padded to 13*64 (BK=64 steps divide exactly)
#define D_H    300
#define NP     320      // D_H padded to multiple of 64
#define D_OUT  10
#define NP2    16       // D_OUT padded to 16
#define EPS    1e-5f
#define NBLK   1024     // blocks in gemm1 and gemm2 grids
#define APAD   44       // LDS A row stride in halfs (proven layout from r0)

typedef _Float16 half8  __attribute__((ext_vector_type(8)));
typedef float    floatx4 __attribute__((ext_vector_type(4)));

// Workspace layout (bytes). Aliases (strictly ordered on one stream):
//   part  aliases oc  (part consumed by k_reduce#1 BEFORE k_gemm2 writes oc)
//   part2 aliases S1  (S1 last read by k_gemm1, BEFORE k_gemm2 writes part2)
#define OFF_S1   ((size_t)0)                       // _Float16[320*832]   = 532480
#define OFF_H    ((size_t)532480)                  // _Float16[65536*320] = 41943040
#define OFF_ST1  (OFF_H + (size_t)41943040)        // float[640]
#define OFF_W2   (OFF_ST1 + (size_t)2560)          // _Float16[16*320]    = 10240
#define OFF_ST2  (OFF_W2 + (size_t)10240)          // float[32]
#define OFF_OC   (OFF_ST2 + (size_t)256)           // float[65536*16]     = 4194304
#define OFF_P1   OFF_OC                            // float[640][1024] (alias, time-disjoint)
#define OFF_P2   OFF_S1                            // float[32][1024]  (alias, time-disjoint)

// ---------------- K0: binarize W1 -> fp16 (+-1), zero-padded to [320][832]
__global__ void k_prep1(const float* __restrict__ W1, _Float16* __restrict__ S1)
{
    int idx = blockIdx.x * 256 + threadIdx.x;      // 0..266239 (1040 blocks)
    int n = idx / KP;
    int k = idx - n * KP;
    float v = 0.0f;
    if (n < D_H && k < D_IN)
        v = (W1[n * D_IN + k] >= 0.0f) ? 1.0f : -1.0f;
    S1[idx] = (_Float16)v;
}

// ---------------- K1: h = x @ S1^T  (M=65536, N=320, K=832pad), fp16 MFMA
// BK=64 K-steps: 13 barriers/block (was 25), 40 MFMA per barrier (was 20),
// 16 KB x-burst per block-step (was 8). Rationale: R2 proved counted vmcnt +
// depth-1.7 register prefetch is NULL -> the uncovered latency under
// chip-wide lockstep bursts exceeds ~2 steps. Longer steps put the HBM
// transfer time (~3000+cy) above the queue-inflated latency, so the in-step
// pipeline (B at step top -> consumed mid-step; x(s+1) staged at step
// bottom; x(s+2) in flight across one barrier) self-covers.
// LDS: 4 tiles of the PROVEN 32-wide stride-44 layout (tiles {0,1} = even
// step k-slices, {2,3} = odd) -> identical bank behavior + bit-identical
// numerics (same k order, same RTNE cvt) vs round 0.

#define PFB(NK)                                                             \
    _Pragma("unroll")                                                       \
    for (int nt = 0; nt < 5; ++nt)                                          \
        bS0[nt] = *(const half8*)(bb + (size_t)nt * 16 * KP + (NK));        \
    _Pragma("unroll")                                                       \
    for (int nt = 0; nt < 5; ++nt)                                          \
        bS1[nt] = *(const half8*)(bb + (size_t)nt * 16 * KP + (NK) + 32);

// thread t stages 16 fp32 cols [KK+sc, KK+sc+16) of row srow; D_IN%16==0 so
// the guard is all-or-nothing per chunk (zeros for the k>=784 pad).
#define LOADA(SET, KK)                                                      \
    _Pragma("unroll")                                                       \
    for (int j = 0; j < 4; ++j) {                                           \
        SET[j] = (floatx4){};                                               \
        if ((KK) + sc < D_IN)                                               \
            SET[j] = *(const floatx4*)(sxp + (KK) + 4 * j);                 \
    }

// global col KK+16*q4+j -> k-slice (q4>>1), col-in-slice (q4&1)*16 + j
#define STOREA(SET, P)                                                      \
    {                                                                       \
        half8 h0, h1;                                                       \
        _Pragma("unroll")                                                   \
        for (int j = 0; j < 4; ++j) {                                       \
            h0[j]     = (_Float16)SET[0][j];                                \
            h0[4 + j] = (_Float16)SET[1][j];                                \
            h1[j]     = (_Float16)SET[2][j];                                \
            h1[4 + j] = (_Float16)SET[3][j];                                \
        }                                                                   \
        *(half8*)&Alds[(P) + stile][srow][scol]     = h0;                   \
        *(half8*)&Alds[(P) + stile][srow][scol + 8] = h1;                   \
    }

#define AFRAG(P, KS)                                                        \
    _Pragma("unroll")                                                       \
    for (int mt = 0; mt < 4; ++mt)                                          \
        a[mt] = *(const half8*)&Alds[(P) + (KS)][mt * 16 + row15][quad * 8];

#define COMPUTE(BV)                                                         \
    _Pragma("unroll")                                                       \
    for (int nt = 0; nt < 5; ++nt)                                          \
        _Pragma("unroll")                                                   \
        for (int mt = 0; mt < 4; ++mt)                                      \
            acc[mt][nt] = __builtin_amdgcn_mfma_f32_16x16x32_f16(           \
                a[mt], BV[nt], acc[mt][nt], 0, 0, 0);

// Publish LDS writes to the workgroup WITHOUT draining vmcnt (in-flight
// global loads survive the barrier); sched fences pin memory ops.
#define BAR()                                                               \
    asm volatile("s_waitcnt lgkmcnt(0)" ::: "memory");                      \
    __builtin_amdgcn_sched_barrier(0);                                      \
    __builtin_amdgcn_s_barrier();                                           \
    __builtin_amdgcn_sched_barrier(0);

__global__ __launch_bounds__(256) void k_gemm1(const float* __restrict__ x,
                                               const _Float16* __restrict__ S1,
                                               _Float16* __restrict__ h,
                                               float* __restrict__ part)
{
    __shared__ _Float16 Alds[4][64][APAD];   // 4 x 5.5 KB
    const int t     = threadIdx.x;
    const int wave  = t >> 6;
    const int lane  = t & 63;
    const int row15 = lane & 15;
    const int quad  = lane >> 4;
    const int m0    = blockIdx.x * 64;

    // staging assignment: thread t -> row t>>2, 16-col chunk (t&3)*16
    const int srow  = t >> 2;
    const int q4    = t & 3;
    const int sc    = q4 * 16;
    const int stile = q4 >> 1;           // which k-slice tile of the pair
    const int scol  = (q4 & 1) * 16;     // col within the 32-wide tile
    const float* sxp = x + (size_t)(m0 + srow) * D_IN + sc;

    // B fragment base (MFMA B layout: lane holds col=row15, k=quad*8..+8)
    const _Float16* bb = S1 + (size_t)(wave * 80 + row15) * KP + quad * 8;

    floatx4 acc[4][5] = {};
    half8   bS0[5], bS1[5];              // current step's B, both k-slices
    half8   a[4];
    floatx4 sA[4], sB[4];                // x staging register sets

    // prologue: tiles{0,1} <- x(0); sB <- x(1) in flight
    LOADA(sA, 0)
    LOADA(sB, 64)
    STOREA(sA, 0)                        // counted vmcnt: waits only sA
    BAR()

    for (int i = 0; i < 6; ++i) {
        const int kk = i * 128;
        // even step s=2i: reads tiles{0,1}; writes {2,3} <- sB = x(s+1)
        PFB(kk)                          // B oldest -> arrives first
        LOADA(sA, kk + 128)              // x(s+2), consumed next step
        AFRAG(0, 0)
        COMPUTE(bS0)
        AFRAG(0, 1)
        COMPUTE(bS1)
        STOREA(sB, 2)
        BAR()
        // odd step s=2i+1: reads {2,3}; writes {0,1} <- sA = x(s+2)
        PFB(kk + 64)
        LOADA(sB, kk + 192)              // i=5 -> 832: guards kill all loads
        AFRAG(2, 0)
        COMPUTE(bS0)
        AFRAG(2, 1)
        COMPUTE(bS1)
        STOREA(sA, 0)
        BAR()
    }
    // tail step 12: reads tiles{0,1} (k=768..831; cols>=784 are zeros)
    PFB(768)
    AFRAG(0, 0)
    COMPUTE(bS0)
    AFRAG(0, 1)
    COMPUTE(bS1)

    // --- epilogue: store h (C/D layout: col=lane&15, row=quad*4+r) + stats
    float s[5] = {}, q[5] = {};
#pragma unroll
    for (int mt = 0; mt < 4; ++mt)
#pragma unroll
        for (int nt = 0; nt < 5; ++nt)
#pragma unroll
            for (int r = 0; r < 4; ++r) {
                float v = acc[mt][nt][r];
                int m = m0 + mt * 16 + quad * 4 + r;
                int n = wave * 80 + nt * 16 + row15;
                h[(size_t)m * NP + n] = (_Float16)v;
                s[nt] += v;
                q[nt] += v * v;
            }
    // reduce over quad (waves own disjoint col ranges -> no cross-wave combine)
#pragma unroll
    for (int nt = 0; nt < 5; ++nt) {
        s[nt] += __shfl_xor(s[nt], 16); s[nt] += __shfl_xor(s[nt], 32);
        q[nt] += __shfl_xor(q[nt], 16); q[nt] += __shfl_xor(q[nt], 32);
    }
    if (quad == 0) {
#pragma unroll
        for (int nt = 0; nt < 5; ++nt) {
            int col = wave * 80 + nt * 16 + row15;
            part[(size_t)col * NBLK + blockIdx.x]        = s[nt];
            part[(size_t)(NP + col) * NBLK + blockIdx.x] = q[nt];
        }
    }
}

// ---------------- K2: contention-free reduce of per-block partials
// (one block per output element; partial stride fixed at NBLK=1024)
__global__ void k_reduce(const float* __restrict__ part, float* __restrict__ st)
{
    __shared__ float red[4];
    const int c = blockIdx.x;
    const int t = threadIdx.x;           // 256
    const float* p = part + (size_t)c * NBLK;
    float s = p[t] + p[t + 256] + p[t + 512] + p[t + 768];
#pragma unroll
    for (int off = 1; off < 64; off <<= 1) s += __shfl_xor(s, off);
    if ((t & 63) == 0) red[t >> 6] = s;
    __syncthreads();
    if (t == 0) st[c] = red[0] + red[1] + red[2] + red[3];
}

// ---------------- K3: fold BN1 scale into binarized W2 -> w2h[16][320] fp16
__global__ void k_prep2(const float* __restrict__ st, const float* __restrict__ gamma1,
                        const float* __restrict__ W2, _Float16* __restrict__ w2h)
{
    int j = threadIdx.x;                 // 0..319
    float mean = st[j] * (1.0f / 65536.0f);
    float var  = st[NP + j] * (1.0f / 65536.0f) - mean * mean;
    float a1   = 0.0f;
    if (j < D_H) a1 = gamma1[j] / sqrtf(var + EPS);
    for (int k = 0; k < NP2; ++k) {
        float w = 0.0f;
        if (k < D_OUT && j < D_H)
            w = (W2[k * D_H + j] >= 0.0f) ? a1 : -a1;
        w2h[k * NP + j] = (_Float16)w;
    }
}

// ---------------- K4: oc = h @ w2h^T  (K=320, N=16) + per-block stat partials
__global__ __launch_bounds__(256) void k_gemm2(const _Float16* __restrict__ h,
                                               const _Float16* __restrict__ w2h,
                                               float* __restrict__ oc,
                                               float* __restrict__ part2)
{
    __shared__ _Float16 Wlds[16][328];   // pad 320->328 to break bank conflicts
    __shared__ float reds[4][16], redq[4][16];
    const int t     = threadIdx.x;
    const int wave  = t >> 6;
    const int lane  = t & 63;
    const int row15 = lane & 15;
    const int quad  = lane >> 4;

    for (int c = t; c < 640; c += 256) { // 16*320/8 chunks
        int r  = c / 40;
        int cc = (c - r * 40) * 8;
        *(half8*)&Wlds[r][cc] = *(const half8*)(w2h + r * NP + cc);
    }
    __syncthreads();

    const int m0 = blockIdx.x * 64 + wave * 16;
    const _Float16* hp = h + (size_t)(m0 + row15) * NP + quad * 8;
    floatx4 acc = {};
#pragma unroll
    for (int kk = 0; kk < NP; kk += 32) {
        half8 a2 = *(const half8*)(hp + kk);
        half8 b2 = *(const half8*)&Wlds[row15][kk + quad * 8];
        acc = __builtin_amdgcn_mfma_f32_16x16x32_f16(a2, b2, acc, 0, 0, 0);
    }
    float s = 0.f, q = 0.f;
#pragma unroll
    for (int r = 0; r < 4; ++r) {
        float v = acc[r];
        oc[(size_t)(m0 + quad * 4 + r) * NP2 + row15] = v;
        s += v; q += v * v;
    }
    s += __shfl_xor(s, 16); s += __shfl_xor(s, 32);
    q += __shfl_xor(q, 16); q += __shfl_xor(q, 32);
    if (lane < 16) { reds[wave][row15] = s; redq[wave][row15] = q; }
    __syncthreads();
    if (t < 16) {
        float S = reds[0][t] + reds[1][t] + reds[2][t] + reds[3][t];
        float Q = redq[0][t] + redq[1][t] + redq[2][t] + redq[3][t];
        part2[(size_t)t * NBLK + blockIdx.x]          = S;
        part2[(size_t)(16 + t) * NBLK + blockIdx.x]   = Q;
    }
}

// ---------------- K5: BN2 epilogue -> out[65536][10] fp32
__global__ void k_final(const float* __restrict__ oc, const float* __restrict__ st2,
                        const float* __restrict__ gamma2, const float* __restrict__ beta2,
                        float* __restrict__ out)
{
    int idx = blockIdx.x * 256 + threadIdx.x;    // 2560*256 == 655360 exactly
    int m = idx / 10;
    int k = idx - m * 10;
    float mean = st2[k] * (1.0f / 65536.0f);
    float var  = st2[16 + k] * (1.0f / 65536.0f) - mean * mean;
    float sc   = gamma2[k] / sqrtf(var + EPS);
    out[idx] = (oc[(size_t)m * NP2 + k] - mean) * sc + beta2[k];
}

extern "C" void kernel_launch(void* const* d_in, const int* in_sizes, int n_in,
                              void* d_out, int out_size, void* d_ws, size_t ws_size,
                              hipStream_t stream)
{
    const float* x      = (const float*)d_in[0];
    const float* W1     = (const float*)d_in[1];
    const float* gamma1 = (const float*)d_in[2];
    // d_in[3] = beta1 : algebraically cancels under BN2's mean subtraction
    const float* W2     = (const float*)d_in[4];
    const float* gamma2 = (const float*)d_in[5];
    const float* beta2  = (const float*)d_in[6];
    float* out = (float*)d_out;

    char* ws = (char*)d_ws;
    _Float16* S1    = (_Float16*)(ws + OFF_S1);
    _Float16* h     = (_Float16*)(ws + OFF_H);
    float*    st1   = (float*)(ws + OFF_ST1);
    _Float16* w2h   = (_Float16*)(ws + OFF_W2);
    float*    st2   = (float*)(ws + OFF_ST2);
    float*    oc    = (float*)(ws + OFF_OC);
    float*    part  = (float*)(ws + OFF_P1);   // aliases oc  (time-disjoint)
    float*    part2 = (float*)(ws + OFF_P2);   // aliases S1  (time-disjoint)

    k_prep1 <<<1040, 256, 0, stream>>>(W1, S1);
    k_gemm1 <<<NBLK, 256, 0, stream>>>(x, S1, h, part);
    k_reduce<<<640, 256, 0, stream>>>(part, st1);
    k_prep2 <<<1, 320, 0, stream>>>(st1, gamma1, W2, w2h);
    k_gemm2 <<<NBLK, 256, 0, stream>>>(h, w2h, oc, part2);
    k_reduce<<<32, 256, 0, stream>>>(part2, st2);
    k_final <<<2560, 256, 0, stream>>>(oc, st2, gamma2, beta2, out);
}